// Round 11
// baseline (626.810 us; speedup 1.0000x reference)
//
#include <hip/hip_runtime.h>

// ============================ DIAGNOSTIC ROUND =============================
// Round-10 verified kernel body (float4 loads + 4-way s-segmentation), run
// THREE times in one dispatch (grid x3). Passes 1,2 recompute ray-shifted
// block assignments and write bit-identical values (benign duplicate writes,
// output unchanged -> still passes correctness).
//
// Purpose: the render dispatch has never appeared in the top-5 counter rows
// (always below the 197us harness fills). Three structural theories (ILP
// pipelining, 2.5x TLP, 4x load granularity) all measured EXACTLY neutral;
// the remaining hypotheses differ in the render kernel's true FETCH_SIZE and
// duration, which we have never observed. Tripling the work forces the
// dispatch into the top-5 WITH counters, and dur_us delta = 2x true T.
//   - per-pass FETCH ~436 MB + T~141us  -> genuine half-rate mystery
//   - per-pass FETCH ~870 MB            -> 2x overfetch, already at BW peak
//   - T ~70us                           -> was already at roofline
// The 21-ray shift per pass de-aligns the three passes' address streams
// (~109 MB apart, concurrent footprint > 256 MB L3) so duplicate passes
// cannot be absorbed by Infinity Cache.
// ===========================================================================

// Problem constants (from reference)
#define NCH   52            // NC
#define NSs   128           // NS (scan length)
#define NRAYS 64
#define INNER 64            // NR*NT = 4*16
#define XS    (3*NCH*INNER) // per-s stride in x       = 9984 floats
#define ZS    (2*NCH*INNER) // per-s stride in z_vals  = 6656 floats
#define NOUT  (NRAYS*NCH*INNER)  // 212992 complex outputs
#define NCG   13            // channel groups of 4 (52/4)
#define NBLK  (NRAYS*NCG)   // 832 blocks per pass
#define PASSES 3

__global__ __launch_bounds__(256) void render_kernel(
    const float* __restrict__ x,
    const float* __restrict__ zv,
    const float* __restrict__ fc,
    float* __restrict__ out)
{
    const int bid  = blockIdx.x;
    const int pass = bid / NBLK;        // 0,1,2 — passes 1,2 are redundant
    const int b    = bid - pass * NBLK;
    const int r0   = b / NCG;
    const int cg   = b - r0 * NCG;
    const int r    = (r0 + pass * 21) & (NRAYS - 1);  // de-align pass streams
    const int t    = threadIdx.x;
    const int seg  = t >> 6;            // wave id = s-segment (0..3)
    const int lane = t & 63;
    const int chof = lane >> 4;         // 0..3: channel within group
    const int idx  = lane & 15;         // float4 position over inner
    const int c    = cg * 4 + chof;

    // float4-unit strides
    const int XS4 = XS / 4;             // 2496
    const int ZS4 = ZS / 4;             // 1664
    const int P4  = (NCH * INNER) / 4;  // 832 (plane offset in x)

    const float4* xp = (const float4*)(x  + (size_t)r * NSs * XS + c * INNER) + idx;
    const float4* zp = (const float4*)(zv + (size_t)r * NSs * ZS + c * INNER) + idx;

    const double C_L    = 299792458.0;
    const double PI_D   = 3.14159265358979323846;
    const float  fcd    = fc[NCH + c];
    const double fc_rev = (double)fcd * 1.0e9 / C_L;   // revolutions per unit dist
    const float  ampc   = (float)(C_L / ((double)fcd * 1.0e9 * 4.0 * PI_D));

    // per-chain state (chains j = inner idx*4 + j)
    float Pre[4], Pim[4], are[4], aim[4], zc[4];
    int s = seg * 32;

    {
        float4 z0 = zp[(size_t)s * ZS4];
        zc[0] = z0.x; zc[1] = z0.y; zc[2] = z0.z; zc[3] = z0.w;
    }
#pragma unroll
    for (int j = 0; j < 4; ++j) { are[j] = 0.0f; aim[j] = 0.0f; }

    if (seg == 0) {
        // s = 0: P[0] = 0 -> no contribution; build f[0] into Q.
        float4 z1  = zp[ZS4];
        float4 ar0 = xp[2 * P4];
        float zn[4] = { z1.x, z1.y, z1.z, z1.w };
        float a0[4] = { ar0.x, ar0.y, ar0.z, ar0.w };
#pragma unroll
        for (int j = 0; j < 4; ++j) {
            float oma = __expf(-a0[j]);            // (1 - alpha[0])
            double u  = fc_rev * (double)(zn[j] - zc[j]);
            u -= floor(u);                         // fractional revolutions
            float uf = (float)u;
            float sn = __builtin_amdgcn_sinf(uf);  // sin(2*pi*u)
            float cs = __builtin_amdgcn_cosf(uf);
            Pre[j] = fmaf(oma, cs, 1e-10f);
            Pim[j] = -oma * sn;
            zc[j]  = zn[j];
        }
        s = 1;
    } else {
#pragma unroll
        for (int j = 0; j < 4; ++j) { Pre[j] = 1.0f; Pim[j] = 0.0f; }
    }

    const int send = (seg + 1) * 32;    // exclusive end

#pragma unroll 2
    for (; s < send; ++s) {
        float4 xre4 = xp[(size_t)s * XS4];
        float4 xim4 = xp[(size_t)s * XS4 + P4];
        float4 ar4  = xp[(size_t)s * XS4 + 2 * P4];
        int    sn_i = (s + 1 < NSs) ? (s + 1) : (NSs - 1); // clamp: f[127] unused
        float4 z4   = zp[(size_t)sn_i * ZS4];

        float xr[4] = { xre4.x, xre4.y, xre4.z, xre4.w };
        float xi[4] = { xim4.x, xim4.y, xim4.z, xim4.w };
        float aa[4] = { ar4.x,  ar4.y,  ar4.z,  ar4.w  };
        float zn[4] = { z4.x,   z4.y,   z4.z,   z4.w   };

#pragma unroll
        for (int j = 0; j < 4; ++j) {
            // contribution for s: ch * amp_decay * (alpha * Q)
            float oma   = __expf(-aa[j]);          // (1 - alpha)
            float alpha = 1.0f - oma;
            float amp   = ampc * __builtin_amdgcn_rcpf(zc[j]);
            float k     = alpha * amp;
            float cre   = k * Pre[j];
            float cim   = k * Pim[j];
            are[j] = fmaf(xr[j], cre, fmaf(-xi[j], cim, are[j]));
            aim[j] = fmaf(xr[j], cim, fmaf( xi[j], cre, aim[j]));

            // fold f[s] into Q
            double u = fc_rev * (double)(zn[j] - zc[j]);
            u -= floor(u);
            float uf = (float)u;
            float sn = __builtin_amdgcn_sinf(uf);
            float cs = __builtin_amdgcn_cosf(uf);
            float fre = fmaf(oma, cs, 1e-10f);
            float fim = -oma * sn;
            float nre = Pre[j] * fre - Pim[j] * fim;
            float nim = fmaf(Pre[j], fim, Pim[j] * fre);
            Pre[j] = nre;
            Pim[j] = nim;
            zc[j]  = zn[j];
        }
    }

    // ---- combine the 4 segments in LDS (verified round-9/10 scheme) ----
    __shared__ float4 comb[3][64][4];
    if (seg > 0) {
        comb[seg - 1][lane][0] = make_float4(are[0], are[1], are[2], are[3]);
        comb[seg - 1][lane][1] = make_float4(aim[0], aim[1], aim[2], aim[3]);
        comb[seg - 1][lane][2] = make_float4(Pre[0], Pre[1], Pre[2], Pre[3]);
        comb[seg - 1][lane][3] = make_float4(Pim[0], Pim[1], Pim[2], Pim[3]);
    }
    __syncthreads();

    if (seg == 0) {
        float ore[4], oim[4];
        {   // o = sum3
            float4 sr = comb[2][lane][0], si = comb[2][lane][1];
            ore[0] = sr.x; ore[1] = sr.y; ore[2] = sr.z; ore[3] = sr.w;
            oim[0] = si.x; oim[1] = si.y; oim[2] = si.z; oim[3] = si.w;
        }
#pragma unroll
        for (int k = 2; k >= 1; --k) {  // o = sum_k + F_k * o
            float4 sr = comb[k - 1][lane][0], si = comb[k - 1][lane][1];
            float4 fr = comb[k - 1][lane][2], fi = comb[k - 1][lane][3];
            float srr[4] = { sr.x, sr.y, sr.z, sr.w };
            float sii[4] = { si.x, si.y, si.z, si.w };
            float frr[4] = { fr.x, fr.y, fr.z, fr.w };
            float fii[4] = { fi.x, fi.y, fi.z, fi.w };
#pragma unroll
            for (int j = 0; j < 4; ++j) {
                float tr = srr[j] + frr[j] * ore[j] - fii[j] * oim[j];
                float ti = sii[j] + frr[j] * oim[j] + fii[j] * ore[j];
                ore[j] = tr; oim[j] = ti;
            }
        }
#pragma unroll
        for (int j = 0; j < 4; ++j) {   // o = sum0 + F0 * o (registers)
            float tr = are[j] + Pre[j] * ore[j] - Pim[j] * oim[j];
            float ti = aim[j] + Pre[j] * oim[j] + Pim[j] * ore[j];
            ore[j] = tr; oim[j] = ti;
        }

        // duplicate passes write identical values — benign
        const int obase = (r * NCH + c) * INNER + idx * 4;
        *(float4*)(out + obase)        = make_float4(ore[0], ore[1], ore[2], ore[3]);
        *(float4*)(out + NOUT + obase) = make_float4(oim[0], oim[1], oim[2], oim[3]);
    }
}

extern "C" void kernel_launch(void* const* d_in, const int* in_sizes, int n_in,
                              void* d_out, int out_size, void* d_ws, size_t ws_size,
                              hipStream_t stream) {
    const float* x  = (const float*)d_in[0];
    const float* zv = (const float*)d_in[1];
    const float* fc = (const float*)d_in[2];
    float* out = (float*)d_out;

    render_kernel<<<NBLK * PASSES, 256, 0, stream>>>(x, zv, fc, out);
}

// Round 13
// 550.902 us; speedup vs baseline: 1.1378x; 1.1378x over previous
//
#include <hip/hip_runtime.h>
#include <stdint.h>

// Problem constants (from reference)
#define NCH   52            // NC
#define NSs   128           // NS
#define NRAYS 64
#define INNER 64            // NR*NT
#define XS    (3*NCH*INNER) // per-s stride in x       = 9984 floats
#define ZS    (2*NCH*INNER) // per-s stride in z_vals  = 6656 floats
#define NOUT  (NRAYS*NCH*INNER)  // 212992 complex outputs
#define CH_PER_RAY (NCH*INNER)   // 3328
#define SEGLEN 32
#define QPT   13            // chains per thread (3328 / 256)

#define XBYTES (3*NCH*INNER*4)   // 39936 = 39 x 1024
#define ZBYTES (NCH*INNER*4)     // 13312 = 13 x 1024
#define XFLOATS (XBYTES/4)       // 9984
#define STEPFLOATS ((XBYTES+ZBYTES)/4)  // 13312 floats per staged step

// Round-11 diagnostic verdict: HBM READ pinned at ~2.7 TB/s regardless of
// concurrency (1x and 3x demand both -> ~2.7; extra demand served by L3),
// with VALU 24% / occupancy 57% idle. Theory: ~3300 de-synced 1KB-granule
// streams at 13-40KB strides kill DRAM page / uTLB locality. Fix: one long
// CONTIGUOUS stream per CU — block = (ray, s-segment), sweeps x[s]+z[s+1]
// planes in address order via global_load_lds (16B), double-buffered LDS,
// counted vmcnt so loads stay in flight across raw s_barriers (T3/T4).
// Segment (sum,F) -> workspace; combine kernel applies the verified
// reassociation out = sum0 + F0*(sum1 + F1*(sum2 + F2*sum3)).

#define GLOAD_LDS16(gsrc, ldst)                                             \
    __builtin_amdgcn_global_load_lds(                                       \
        (const __attribute__((address_space(1))) uint32_t*)(gsrc),          \
        (__attribute__((address_space(3))) uint32_t*)(ldst), 16, 0, 0)

__global__ __launch_bounds__(256, 1) void render_seg_kernel(
    const float* __restrict__ x,
    const float* __restrict__ zv,
    const float* __restrict__ fc,
    float4* __restrict__ ws)
{
    __shared__ float lds[2][STEPFLOATS];   // 2 x 53248 B = 104 KiB

    const int blk = blockIdx.x;            // 0..255  (1 block per CU)
    const int g   = blk & 3;               // s-segment 0..3
    const int r   = blk >> 2;              // ray 0..63
    const int t   = threadIdx.x;
    const int w   = t >> 6;                // wave 0..3
    const int l   = t & 63;                // lane

    const int s0   = g * SEGLEN;
    const int send = s0 + SEGLEN;

    const float* xray = x  + (size_t)r * NSs * XS;
    const float* zray = zv + (size_t)r * NSs * ZS;

    // ---- per-chain init: chain q -> channel ch = 4q + w, inner = l ----
    float Pre[QPT], Pim[QPT], zc[QPT], accre[QPT], accim[QPT], fcd_[QPT];
#pragma unroll
    for (int q = 0; q < QPT; ++q) {
        const int ch = 4 * q + w;
        fcd_[q]  = fc[NCH + ch];
        zc[q]    = zray[(size_t)s0 * ZS + ch * INNER + l];   // z[r][s0][ch][l]
        Pre[q]   = 1.0f;  Pim[q] = 0.0f;   // segment-local exclusive product
        accre[q] = 0.0f;  accim[q] = 0.0f;
    }

    const double REV = 1.0e9 / 299792458.0;                 // rev per unit dist / fc
    const float  Kc  = (float)(299792458.0 /
                       (1.0e9 * 4.0 * 3.14159265358979323846)); // amp = Kc/(fc*z)

    // ---- staging: step s = x[s] plane (39 KiB) + z[min(s+1,127)] (13 KiB),
    //      52 x 1KB chunks in ADDRESS ORDER; waves 0-2 -> x, wave 3 -> z ----
    auto STAGE = [&](int buf, int s) {
        const int sz = (s + 1 < NSs) ? s + 1 : NSs - 1;     // f[127] unused
        const char* xsrc = (const char*)(xray + (size_t)s  * XS);
        const char* zsrc = (const char*)(zray + (size_t)sz * ZS);
        char* base = (char*)&lds[buf][0];
#pragma unroll
        for (int k = 0; k < 13; ++k) {
            if (w < 3) {
                const int off = ((w * 13 + k) << 10);
                GLOAD_LDS16(xsrc + off + (l << 4), base + off);
            } else {
                const int off = (k << 10);
                GLOAD_LDS16(zsrc + off + (l << 4), base + XBYTES + off);
            }
        }
    };

    STAGE(0, s0);
    int buf = 0;

    for (int s = s0; s < send; ++s) {
        const bool more = (s + 1 < send);
        if (more) STAGE(buf ^ 1, s + 1);

        // wait THIS step's 13 DMA loads (newest 13 = next step's stay in flight)
        if (more) asm volatile("s_waitcnt vmcnt(13)" ::: "memory");
        else      asm volatile("s_waitcnt vmcnt(0)"  ::: "memory");
        __builtin_amdgcn_s_barrier();
        __builtin_amdgcn_sched_barrier(0);   // keep ds_reads below the barrier

        const float* xl = &lds[buf][0];
        const float* zl = &lds[buf][XFLOATS];
        const bool contrib = (s != 0);       // P[0] = 0: s=0 folds f[0] only

#pragma unroll
        for (int q = 0; q < QPT; ++q) {
            const int ch   = 4 * q + w;
            const int base = ch * INNER + l;
            const float xre = xl[base];
            const float xim = xl[NCH * INNER + base];
            const float ar  = xl[2 * NCH * INNER + base];
            const float zn  = zl[base];                     // z[s+1]

            const float oma   = __expf(-ar);                // (1 - alpha)
            const float alpha = 1.0f - oma;
            const float amp   = Kc * __builtin_amdgcn_rcpf(fcd_[q] * zc[q]);
            const float k     = alpha * amp;
            if (contrib) {
                const float cre = k * Pre[q];
                const float cim = k * Pim[q];
                accre[q] = fmaf(xre, cre, fmaf(-xim, cim, accre[q]));
                accim[q] = fmaf(xre, cim, fmaf( xim, cre, accim[q]));
            }
            // fold f[s] into the running product
            double u = ((double)fcd_[q] * REV) * (double)(zn - zc[q]);
            u -= floor(u);                                  // frac revolutions
            const float uf  = (float)u;
            const float sn  = __builtin_amdgcn_sinf(uf);    // sin(2*pi*u)
            const float cs  = __builtin_amdgcn_cosf(uf);
            const float fre = fmaf(oma, cs, 1e-10f);
            const float fim = -oma * sn;
            const float nre = Pre[q] * fre - Pim[q] * fim;
            const float nim = fmaf(Pre[q], fim, Pim[q] * fre);
            Pre[q] = nre;  Pim[q] = nim;  zc[q] = zn;
        }

        __builtin_amdgcn_sched_barrier(0);
        __builtin_amdgcn_s_barrier();        // buffer free before next overwrite
        buf ^= 1;
    }

    // ---- emit (sum, F) per chain:  ws[g*NOUT + r*3328 + ch*64 + l] ----
#pragma unroll
    for (int q = 0; q < QPT; ++q) {
        const int ch = 4 * q + w;
        const size_t idx = (size_t)g * NOUT + (size_t)r * CH_PER_RAY
                         + ch * INNER + l;
        ws[idx] = make_float4(accre[q], accim[q], Pre[q], Pim[q]);
    }
}

// out = sum0 + F0*(sum1 + F1*(sum2 + F2*sum3))   (verified reassociation)
__global__ __launch_bounds__(256) void combine_kernel(
    const float4* __restrict__ ws, float* __restrict__ out)
{
    const int tid = blockIdx.x * 256 + threadIdx.x;     // r*3328 + ch*64 + l
    const float4 c0 = ws[tid];
    const float4 c1 = ws[NOUT + tid];
    const float4 c2 = ws[2 * NOUT + tid];
    const float4 c3 = ws[3 * NOUT + tid];
    float ore = c3.x, oim = c3.y, tt;
    tt  = c2.x + c2.z * ore - c2.w * oim;
    oim = c2.y + c2.z * oim + c2.w * ore;  ore = tt;
    tt  = c1.x + c1.z * ore - c1.w * oim;
    oim = c1.y + c1.z * oim + c1.w * ore;  ore = tt;
    tt  = c0.x + c0.z * ore - c0.w * oim;
    oim = c0.y + c0.z * oim + c0.w * ore;  ore = tt;
    out[tid]        = ore;   // real plane
    out[NOUT + tid] = oim;   // imag plane
}

// ---------------- fallback (round-10 verified kernel) if ws too small -----
#define NCG  13
#define NBLK (NRAYS*NCG)
__global__ __launch_bounds__(256) void render_fallback(
    const float* __restrict__ x, const float* __restrict__ zv,
    const float* __restrict__ fc, float* __restrict__ out)
{
    const int b    = blockIdx.x;
    const int r    = b / NCG;
    const int cg   = b - r * NCG;
    const int t    = threadIdx.x;
    const int seg  = t >> 6;
    const int lane = t & 63;
    const int chof = lane >> 4;
    const int idx  = lane & 15;
    const int c    = cg * 4 + chof;
    const int XS4 = XS / 4, ZS4 = ZS / 4, P4 = (NCH * INNER) / 4;
    const float4* xp = (const float4*)(x  + (size_t)r * NSs * XS + c * INNER) + idx;
    const float4* zp = (const float4*)(zv + (size_t)r * NSs * ZS + c * INNER) + idx;
    const double C_L = 299792458.0, PI_D = 3.14159265358979323846;
    const float  fcd = fc[NCH + c];
    const double fc_rev = (double)fcd * 1.0e9 / C_L;
    const float  ampc   = (float)(C_L / ((double)fcd * 1.0e9 * 4.0 * PI_D));
    float Pre[4], Pim[4], are[4], aim[4], zc[4];
    int s = seg * 32;
    { float4 z0 = zp[(size_t)s * ZS4]; zc[0]=z0.x; zc[1]=z0.y; zc[2]=z0.z; zc[3]=z0.w; }
#pragma unroll
    for (int j = 0; j < 4; ++j) { are[j] = 0.0f; aim[j] = 0.0f; }
    if (seg == 0) {
        float4 z1 = zp[ZS4]; float4 ar0 = xp[2 * P4];
        float zn[4] = { z1.x, z1.y, z1.z, z1.w };
        float a0[4] = { ar0.x, ar0.y, ar0.z, ar0.w };
#pragma unroll
        for (int j = 0; j < 4; ++j) {
            float oma = __expf(-a0[j]);
            double u = fc_rev * (double)(zn[j] - zc[j]); u -= floor(u);
            float uf = (float)u;
            float sn = __builtin_amdgcn_sinf(uf), cs = __builtin_amdgcn_cosf(uf);
            Pre[j] = fmaf(oma, cs, 1e-10f); Pim[j] = -oma * sn; zc[j] = zn[j];
        }
        s = 1;
    } else {
#pragma unroll
        for (int j = 0; j < 4; ++j) { Pre[j] = 1.0f; Pim[j] = 0.0f; }
    }
    const int send = (seg + 1) * 32;
#pragma unroll 2
    for (; s < send; ++s) {
        float4 xre4 = xp[(size_t)s * XS4];
        float4 xim4 = xp[(size_t)s * XS4 + P4];
        float4 ar4  = xp[(size_t)s * XS4 + 2 * P4];
        int    sn_i = (s + 1 < NSs) ? (s + 1) : (NSs - 1);
        float4 z4   = zp[(size_t)sn_i * ZS4];
        float xr[4] = { xre4.x, xre4.y, xre4.z, xre4.w };
        float xi[4] = { xim4.x, xim4.y, xim4.z, xim4.w };
        float aa[4] = { ar4.x,  ar4.y,  ar4.z,  ar4.w  };
        float zn[4] = { z4.x,   z4.y,   z4.z,   z4.w   };
#pragma unroll
        for (int j = 0; j < 4; ++j) {
            float oma = __expf(-aa[j]);
            float alpha = 1.0f - oma;
            float amp = ampc * __builtin_amdgcn_rcpf(zc[j]);
            float k = alpha * amp;
            float cre = k * Pre[j], cim = k * Pim[j];
            are[j] = fmaf(xr[j], cre, fmaf(-xi[j], cim, are[j]));
            aim[j] = fmaf(xr[j], cim, fmaf( xi[j], cre, aim[j]));
            double u = fc_rev * (double)(zn[j] - zc[j]); u -= floor(u);
            float uf = (float)u;
            float sn = __builtin_amdgcn_sinf(uf), cs = __builtin_amdgcn_cosf(uf);
            float fre = fmaf(oma, cs, 1e-10f), fim = -oma * sn;
            float nre = Pre[j] * fre - Pim[j] * fim;
            float nim = fmaf(Pre[j], fim, Pim[j] * fre);
            Pre[j] = nre; Pim[j] = nim; zc[j] = zn[j];
        }
    }
    __shared__ float4 comb[3][64][4];
    if (seg > 0) {
        comb[seg-1][lane][0] = make_float4(are[0], are[1], are[2], are[3]);
        comb[seg-1][lane][1] = make_float4(aim[0], aim[1], aim[2], aim[3]);
        comb[seg-1][lane][2] = make_float4(Pre[0], Pre[1], Pre[2], Pre[3]);
        comb[seg-1][lane][3] = make_float4(Pim[0], Pim[1], Pim[2], Pim[3]);
    }
    __syncthreads();
    if (seg == 0) {
        float ore[4], oim[4];
        { float4 sr = comb[2][lane][0], si = comb[2][lane][1];
          ore[0]=sr.x; ore[1]=sr.y; ore[2]=sr.z; ore[3]=sr.w;
          oim[0]=si.x; oim[1]=si.y; oim[2]=si.z; oim[3]=si.w; }
#pragma unroll
        for (int k = 2; k >= 1; --k) {
            float4 sr = comb[k-1][lane][0], si = comb[k-1][lane][1];
            float4 fr = comb[k-1][lane][2], fi = comb[k-1][lane][3];
            float srr[4]={sr.x,sr.y,sr.z,sr.w}, sii[4]={si.x,si.y,si.z,si.w};
            float frr[4]={fr.x,fr.y,fr.z,fr.w}, fii[4]={fi.x,fi.y,fi.z,fi.w};
#pragma unroll
            for (int j = 0; j < 4; ++j) {
                float tr = srr[j] + frr[j]*ore[j] - fii[j]*oim[j];
                float ti = sii[j] + frr[j]*oim[j] + fii[j]*ore[j];
                ore[j] = tr; oim[j] = ti;
            }
        }
#pragma unroll
        for (int j = 0; j < 4; ++j) {
            float tr = are[j] + Pre[j]*ore[j] - Pim[j]*oim[j];
            float ti = aim[j] + Pre[j]*oim[j] + Pim[j]*ore[j];
            ore[j] = tr; oim[j] = ti;
        }
        const int obase = (r * NCH + c) * INNER + idx * 4;
        *(float4*)(out + obase)        = make_float4(ore[0], ore[1], ore[2], ore[3]);
        *(float4*)(out + NOUT + obase) = make_float4(oim[0], oim[1], oim[2], oim[3]);
    }
}

extern "C" void kernel_launch(void* const* d_in, const int* in_sizes, int n_in,
                              void* d_out, int out_size, void* d_ws, size_t ws_size,
                              hipStream_t stream) {
    const float* x  = (const float*)d_in[0];
    const float* zv = (const float*)d_in[1];
    const float* fc = (const float*)d_in[2];
    float* out = (float*)d_out;

    const size_t ws_need = (size_t)4 * NOUT * sizeof(float4);   // 13.6 MB
    if (d_ws && ws_size >= ws_need) {
        float4* ws = (float4*)d_ws;
        render_seg_kernel<<<NRAYS * 4, 256, 0, stream>>>(x, zv, fc, ws);
        combine_kernel<<<NOUT / 256, 256, 0, stream>>>(ws, out);
    } else {
        render_fallback<<<NBLK, 256, 0, stream>>>(x, zv, fc, out);
    }
}